// Round 2
// baseline (2126.497 us; speedup 1.0000x reference)
//
#include <hip/hip_runtime.h>

// NonLinearReadoutBlock: fused gated irreps MLP, f32.
// Block = 256 threads = 64 rows x 4 column-group lanes (q).
// LDS: R (49KB) staged x0/x1/x2 tiles (padded strides), G (24KB) gates.
// Second-layer outputs reduced across q-lanes via __shfl_xor (no LDS roundtrip).

__global__ __launch_bounds__(256, 2)
void nlrb_fused(const float* __restrict__ x0,
                const float* __restrict__ x1,
                const float* __restrict__ x2,
                const float* __restrict__ W1s,
                const float* __restrict__ W1v1,
                const float* __restrict__ W1v2,
                const float* __restrict__ W2s,
                const float* __restrict__ W2v1,
                const float* __restrict__ W2v2,
                float* __restrict__ out)
{
    __shared__ float R[64 * 196];   // x0 as [64][132] / x1 as [64][196] / x2 as [64][164]
    __shared__ float G[64 * 96];    // gates: g1 [0..63], g2 [64..95] per row

    const int t = threadIdx.x;
    const int r = t >> 2;           // row within tile, 0..63
    const int q = t & 3;            // column group, 0..3
    const long n0 = (long)blockIdx.x * 64;
    const long n  = n0 + r;

    // ---------- stage x0 tile -> R [64][132]
    {
        const float* src = x0 + n0 * 128;
#pragma unroll
        for (int m = 0; m < 8; ++m) {
            const int g = (m * 256 + t) * 4;
            const float4 v = *(const float4*)(src + g);
            const int row = g >> 7;
            const int col = g & 127;
            *(float4*)(&R[row * 132 + col]) = v;
        }
    }
    __syncthreads();

    // ---------- h0 GEMM: this thread owns cols q*56 .. q*56+55
    float acc[56];
#pragma unroll
    for (int j = 0; j < 56; ++j) acc[j] = 0.0f;
    {
        const float* wb = W1s + q * 56;
        for (int k4 = 0; k4 < 32; ++k4) {
            const float4 a4 = *(const float4*)(&R[r * 132 + k4 * 4]);
#pragma unroll
            for (int kk = 0; kk < 4; ++kk) {
                const float a = kk == 0 ? a4.x : kk == 1 ? a4.y : kk == 2 ? a4.z : a4.w;
                const float* wr = wb + (k4 * 4 + kk) * 224;
#pragma unroll
                for (int m = 0; m < 14; ++m) {
                    const float4 w = *(const float4*)(wr + m * 4);
                    acc[m * 4 + 0] = fmaf(a, w.x, acc[m * 4 + 0]);
                    acc[m * 4 + 1] = fmaf(a, w.y, acc[m * 4 + 1]);
                    acc[m * 4 + 2] = fmaf(a, w.z, acc[m * 4 + 2]);
                    acc[m * 4 + 3] = fmaf(a, w.w, acc[m * 4 + 3]);
                }
            }
        }
    }

    // ---------- issue x1 tile loads early (held in regs across activation math)
    float4 xv[12];
    {
        const float* src = x1 + n0 * 192;
#pragma unroll
        for (int m = 0; m < 12; ++m) {
            const int g = (m * 256 + t) * 4;
            xv[m] = *(const float4*)(src + g);
        }
    }

    // ---------- activations: silu -> o0 partials, sigmoid -> gate LDS
    const float S0 = 0.08838834764831845f;   // 1/sqrt(128)
    float po0[16];
#pragma unroll
    for (int c = 0; c < 16; ++c) po0[c] = 0.0f;
#pragma unroll
    for (int j = 0; j < 56; ++j) {
        const int col = q * 56 + j;
        const float h = acc[j] * S0;
        const float sg = 1.0f / (1.0f + __expf(-h));
        if (col < 128) {
            const float s = h * sg;                        // silu
            const float* w2 = W2s + col * 16;
#pragma unroll
            for (int m = 0; m < 4; ++m) {
                const float4 w = *(const float4*)(w2 + m * 4);
                po0[m * 4 + 0] = fmaf(s, w.x, po0[m * 4 + 0]);
                po0[m * 4 + 1] = fmaf(s, w.y, po0[m * 4 + 1]);
                po0[m * 4 + 2] = fmaf(s, w.z, po0[m * 4 + 2]);
                po0[m * 4 + 3] = fmaf(s, w.w, po0[m * 4 + 3]);
            }
        } else {
            G[r * 96 + (col - 128)] = sg;                  // sigmoid gate
        }
    }

    __syncthreads();            // all x0 reads finished; safe to overwrite R

    // ---------- write x1 tile -> R [64][196]
#pragma unroll
    for (int m = 0; m < 12; ++m) {
        const int g = (m * 256 + t) * 4;
        const int row = g / 192;
        const int col = g - row * 192;
        *(float4*)(&R[row * 196 + col]) = xv[m];
    }

    // ---------- o0 reduce across q lanes + store
#pragma unroll
    for (int c = 0; c < 16; ++c) {
        po0[c] += __shfl_xor(po0[c], 1);
        po0[c] += __shfl_xor(po0[c], 2);
    }
    if (q == 0) {
        float* o = out + n * 144;
#pragma unroll
        for (int m = 0; m < 4; ++m) {
            *(float4*)(o + m * 4) = make_float4(po0[m * 4 + 0] * S0, po0[m * 4 + 1] * S0,
                                                po0[m * 4 + 2] * S0, po0[m * 4 + 3] * S0);
        }
    }

    __syncthreads();            // x1 tile + gates visible

    // ---------- h1 GEMM: this thread owns w = q*16 .. q*16+15, i = 0..2
    float a1[48];
#pragma unroll
    for (int e = 0; e < 48; ++e) a1[e] = 0.0f;
    {
        const float* wb = W1v1 + q * 16;
        for (int u = 0; u < 64; ++u) {
            const float xi0 = R[r * 196 + u * 3 + 0];
            const float xi1 = R[r * 196 + u * 3 + 1];
            const float xi2 = R[r * 196 + u * 3 + 2];
            const float* wr = wb + u * 64;
#pragma unroll
            for (int m = 0; m < 4; ++m) {
                const float4 w = *(const float4*)(wr + m * 4);
#define FMA3(IDX, WC) \
                a1[(IDX) * 3 + 0] = fmaf(xi0, WC, a1[(IDX) * 3 + 0]); \
                a1[(IDX) * 3 + 1] = fmaf(xi1, WC, a1[(IDX) * 3 + 1]); \
                a1[(IDX) * 3 + 2] = fmaf(xi2, WC, a1[(IDX) * 3 + 2]);
                FMA3(m * 4 + 0, w.x)
                FMA3(m * 4 + 1, w.y)
                FMA3(m * 4 + 2, w.z)
                FMA3(m * 4 + 3, w.w)
#undef FMA3
            }
        }
    }

    // ---------- issue x2 tile loads early
    float4 xw[10];
    {
        const float* src = x2 + n0 * 160;
#pragma unroll
        for (int m = 0; m < 10; ++m) {
            const int g = (m * 256 + t) * 4;
            xw[m] = *(const float4*)(src + g);
        }
    }

    // ---------- gate1 + o1 partials
    float po1[48];
#pragma unroll
    for (int e = 0; e < 48; ++e) po1[e] = 0.0f;
#pragma unroll
    for (int ww = 0; ww < 16; ++ww) {
        const int w = q * 16 + ww;
        const float gv = G[r * 96 + w];
        const float v0 = a1[ww * 3 + 0] * gv;
        const float v1 = a1[ww * 3 + 1] * gv;
        const float v2 = a1[ww * 3 + 2] * gv;
        const float* w2 = W2v1 + w * 16;
#pragma unroll
        for (int m = 0; m < 4; ++m) {
            const float4 wv = *(const float4*)(w2 + m * 4);
#define PFMA3(IDX, WC) \
            po1[(IDX) * 3 + 0] = fmaf(v0, WC, po1[(IDX) * 3 + 0]); \
            po1[(IDX) * 3 + 1] = fmaf(v1, WC, po1[(IDX) * 3 + 1]); \
            po1[(IDX) * 3 + 2] = fmaf(v2, WC, po1[(IDX) * 3 + 2]);
            PFMA3(m * 4 + 0, wv.x)
            PFMA3(m * 4 + 1, wv.y)
            PFMA3(m * 4 + 2, wv.z)
            PFMA3(m * 4 + 3, wv.w)
#undef PFMA3
        }
    }

    const float S1 = 0.015625f;   // (1/sqrt(64))^2
#pragma unroll
    for (int e = 0; e < 48; ++e) {
        po1[e] += __shfl_xor(po1[e], 1);
        po1[e] += __shfl_xor(po1[e], 2);
    }
    if (q == 0) {
        float* o = out + n * 144 + 16;
#pragma unroll
        for (int m = 0; m < 12; ++m) {
            *(float4*)(o + m * 4) = make_float4(po1[m * 4 + 0] * S1, po1[m * 4 + 1] * S1,
                                                po1[m * 4 + 2] * S1, po1[m * 4 + 3] * S1);
        }
    }

    __syncthreads();            // all x1 reads finished

    // ---------- write x2 tile -> R [64][164]
#pragma unroll
    for (int m = 0; m < 10; ++m) {
        const int g = (m * 256 + t) * 4;
        const int row = g / 160;
        const int col = g - row * 160;
        *(float4*)(&R[row * 164 + col]) = xw[m];
    }
    __syncthreads();            // x2 tile visible

    // ---------- h2 GEMM: this thread owns w = q*8 .. q*8+7, i = 0..4
    float a2[40];
#pragma unroll
    for (int e = 0; e < 40; ++e) a2[e] = 0.0f;
    {
        const float* wb = W1v2 + q * 8;
        for (int u = 0; u < 32; ++u) {
            float y[5];
#pragma unroll
            for (int i = 0; i < 5; ++i) y[i] = R[r * 164 + u * 5 + i];
            const float* wr = wb + u * 32;
#pragma unroll
            for (int m = 0; m < 2; ++m) {
                const float4 w = *(const float4*)(wr + m * 4);
#define FMA5(IDX, WC) { \
                a2[(IDX) * 5 + 0] = fmaf(y[0], WC, a2[(IDX) * 5 + 0]); \
                a2[(IDX) * 5 + 1] = fmaf(y[1], WC, a2[(IDX) * 5 + 1]); \
                a2[(IDX) * 5 + 2] = fmaf(y[2], WC, a2[(IDX) * 5 + 2]); \
                a2[(IDX) * 5 + 3] = fmaf(y[3], WC, a2[(IDX) * 5 + 3]); \
                a2[(IDX) * 5 + 4] = fmaf(y[4], WC, a2[(IDX) * 5 + 4]); }
                FMA5(m * 4 + 0, w.x)
                FMA5(m * 4 + 1, w.y)
                FMA5(m * 4 + 2, w.z)
                FMA5(m * 4 + 3, w.w)
#undef FMA5
            }
        }
    }

    // ---------- gate2 + o2 partials
    float po2[80];
#pragma unroll
    for (int e = 0; e < 80; ++e) po2[e] = 0.0f;
#pragma unroll
    for (int ww = 0; ww < 8; ++ww) {
        const int w = q * 8 + ww;
        const float gv = G[r * 96 + 64 + w];
        float v[5];
#pragma unroll
        for (int i = 0; i < 5; ++i) v[i] = a2[ww * 5 + i] * gv;
        const float* w2 = W2v2 + w * 16;
#pragma unroll
        for (int m = 0; m < 4; ++m) {
            const float4 wv = *(const float4*)(w2 + m * 4);
#define PFMA5(IDX, WC) { \
            po2[(IDX) * 5 + 0] = fmaf(v[0], WC, po2[(IDX) * 5 + 0]); \
            po2[(IDX) * 5 + 1] = fmaf(v[1], WC, po2[(IDX) * 5 + 1]); \
            po2[(IDX) * 5 + 2] = fmaf(v[2], WC, po2[(IDX) * 5 + 2]); \
            po2[(IDX) * 5 + 3] = fmaf(v[3], WC, po2[(IDX) * 5 + 3]); \
            po2[(IDX) * 5 + 4] = fmaf(v[4], WC, po2[(IDX) * 5 + 4]); }
            PFMA5(m * 4 + 0, wv.x)
            PFMA5(m * 4 + 1, wv.y)
            PFMA5(m * 4 + 2, wv.z)
            PFMA5(m * 4 + 3, wv.w)
#undef PFMA5
        }
    }

    const float S2 = 0.03125f;    // (1/sqrt(32))^2
#pragma unroll
    for (int e = 0; e < 80; ++e) {
        po2[e] += __shfl_xor(po2[e], 1);
        po2[e] += __shfl_xor(po2[e], 2);
    }
    if (q == 0) {
        float* o = out + n * 144 + 64;
#pragma unroll
        for (int m = 0; m < 20; ++m) {
            *(float4*)(o + m * 4) = make_float4(po2[m * 4 + 0] * S2, po2[m * 4 + 1] * S2,
                                                po2[m * 4 + 2] * S2, po2[m * 4 + 3] * S2);
        }
    }
}

extern "C" void kernel_launch(void* const* d_in, const int* in_sizes, int n_in,
                              void* d_out, int out_size, void* d_ws, size_t ws_size,
                              hipStream_t stream)
{
    (void)n_in; (void)d_ws; (void)ws_size; (void)out_size;
    const float* x0   = (const float*)d_in[0];
    const float* x1   = (const float*)d_in[1];
    const float* x2   = (const float*)d_in[2];
    const float* W1s  = (const float*)d_in[3];
    const float* W1v1 = (const float*)d_in[4];
    const float* W1v2 = (const float*)d_in[5];
    const float* W2s  = (const float*)d_in[6];
    const float* W2v1 = (const float*)d_in[7];
    const float* W2v2 = (const float*)d_in[8];
    float* out = (float*)d_out;

    const int N = in_sizes[0] / 128;   // 200000
    const int nblocks = N / 64;        // 3125 (exact: 64*3125 = 200000)
    hipLaunchKernelGGL(nlrb_fused, dim3(nblocks), dim3(256), 0, stream,
                       x0, x1, x2, W1s, W1v1, W1v2, W2s, W2v1, W2v2, out);
}